// Round 1
// baseline (6643.464 us; speedup 1.0000x reference)
//
#include <hip/hip_runtime.h>
#include <math.h>

// Problem constants
#define BB 256
#define LL 200
#define HH 256
#define EE 512
#define NSTATE 16
#define KCONV 4
#define RR 16
#define NLAYER 2
#define VV 150000
#define TT 300            // L + L/2
#define MTOK (BB*TT)      // 76800 tokens

// ---------------------------------------------------------------------------
// helpers
// ---------------------------------------------------------------------------
__device__ __forceinline__ float siluf(float x) {
    return x / (1.0f + expf(-x));
}
__device__ __forceinline__ float softplusf(float x) {
    // stable: max(x,0) + log1p(exp(-|x|))  (== logaddexp(x,0))
    return fmaxf(x, 0.0f) + log1pf(expf(-fabsf(x)));
}
__device__ __forceinline__ float geluf(float x) {
    return 0.5f * x * (1.0f + erff(x * 0.70710678118654752440f));
}

// block (256 threads) reduction of two values simultaneously
__device__ __forceinline__ void block_reduce2(float& a, float& b) {
    __shared__ float ra[4], rb[4];
    #pragma unroll
    for (int o = 32; o > 0; o >>= 1) {
        a += __shfl_down(a, o, 64);
        b += __shfl_down(b, o, 64);
    }
    int lane = threadIdx.x & 63, w = threadIdx.x >> 6;
    if (lane == 0) { ra[w] = a; rb[w] = b; }
    __syncthreads();
    a = ra[0] + ra[1] + ra[2] + ra[3];
    b = rb[0] + rb[1] + rb[2] + rb[3];
}

// ---------------------------------------------------------------------------
// 1. embedding gather (with interleave) + LayerNorm -> h (B,T,H)
// one block per token, 256 threads (H=256)
// ---------------------------------------------------------------------------
__global__ __launch_bounds__(256)
void embed_ln_kernel(const int* __restrict__ item_seq,
                     const float* __restrict__ item_emb,
                     const float* __restrict__ ln_w,
                     const float* __restrict__ ln_b,
                     float* __restrict__ h) {
    int tok = blockIdx.x;            // 0..MTOK-1
    int b = tok / TT, p = tok - b * TT;
    int k = p / 3, r = p - 3 * k;
    int item;
    if (r == 2) item = VV - 1;       // user token: -1 + V
    else        item = item_seq[b * LL + 2 * k + r];
    int tid = threadIdx.x;
    float x = item_emb[(long)item * HH + tid];
    float s1 = x, s2 = x * x;
    block_reduce2(s1, s2);
    float m = s1 * (1.0f / HH);
    float var = s2 * (1.0f / HH) - m * m;
    float inv = rsqrtf(var + 1e-12f);
    h[(long)tok * HH + tid] = (x - m) * inv * ln_w[tid] + ln_b[tid];
}

// ---------------------------------------------------------------------------
// 2. residual add + LayerNorm: h = LN(tmp + h)
// ---------------------------------------------------------------------------
__global__ __launch_bounds__(256)
void add_ln_kernel(const float* __restrict__ tmp,
                   float* __restrict__ h,
                   const float* __restrict__ w,
                   const float* __restrict__ bnorm) {
    int tok = blockIdx.x;
    int tid = threadIdx.x;
    long idx = (long)tok * HH + tid;
    float x = tmp[idx] + h[idx];
    float s1 = x, s2 = x * x;
    block_reduce2(s1, s2);
    float m = s1 * (1.0f / HH);
    float var = s2 * (1.0f / HH) - m * m;
    float inv = rsqrtf(var + 1e-12f);
    h[idx] = (x - m) * inv * w[tid] + bnorm[tid];
}

// ---------------------------------------------------------------------------
// 3. generic tiled fp32 GEMM: C[M,N] = act( A[M,K] @ W[N,K]^T + bias )
//    AMODE 0: A plain.  AMODE 1: A elem = A[m,k] * silu(A2[m,k])
//    EPI 0: none.       EPI 1: exact GELU
//    64x64 tile, BK=16, 256 threads, 4x4 per thread
// ---------------------------------------------------------------------------
template <int AMODE, int EPI>
__global__ __launch_bounds__(256)
void gemm_kernel(const float* __restrict__ A, int lda,
                 const float* __restrict__ A2, int lda2,
                 const float* __restrict__ W,
                 const float* __restrict__ bias,
                 float* __restrict__ C, int ldc,
                 int M, int N, int Kd) {
    __shared__ float As[16][64];
    __shared__ float Bs[16][64];
    int bm = blockIdx.x * 64;
    int bn = blockIdx.y * 64;
    int tid = threadIdx.x;
    int tx = tid & 15, ty = tid >> 4;
    int lrow = tid >> 2;            // 0..63
    int lcol = (tid & 3) * 4;       // 0,4,8,12

    float acc[4][4] = {{0.f}};

    for (int k0 = 0; k0 < Kd; k0 += 16) {
        // ---- load A tile (64 rows x 16 k) ----
        {
            long gr = bm + lrow;
            const float* ap = A + gr * (long)lda + k0 + lcol;
            float4 a4 = *(const float4*)ap;
            if (AMODE == 1) {
                const float* zp = A2 + gr * (long)lda2 + k0 + lcol;
                float4 z4 = *(const float4*)zp;
                a4.x *= siluf(z4.x);
                a4.y *= siluf(z4.y);
                a4.z *= siluf(z4.z);
                a4.w *= siluf(z4.w);
            }
            As[lcol + 0][lrow] = a4.x;
            As[lcol + 1][lrow] = a4.y;
            As[lcol + 2][lrow] = a4.z;
            As[lcol + 3][lrow] = a4.w;
        }
        // ---- load W tile (64 n-rows x 16 k) ----
        {
            int gr = bn + lrow;
            float4 b4 = make_float4(0.f, 0.f, 0.f, 0.f);
            if (gr < N) b4 = *(const float4*)(W + (long)gr * Kd + k0 + lcol);
            Bs[lcol + 0][lrow] = b4.x;
            Bs[lcol + 1][lrow] = b4.y;
            Bs[lcol + 2][lrow] = b4.z;
            Bs[lcol + 3][lrow] = b4.w;
        }
        __syncthreads();
        #pragma unroll
        for (int kk = 0; kk < 16; ++kk) {
            float4 a4 = *(const float4*)&As[kk][ty * 4];
            float4 b4 = *(const float4*)&Bs[kk][tx * 4];
            float av[4] = {a4.x, a4.y, a4.z, a4.w};
            float bv[4] = {b4.x, b4.y, b4.z, b4.w};
            #pragma unroll
            for (int i = 0; i < 4; ++i)
                #pragma unroll
                for (int j = 0; j < 4; ++j)
                    acc[i][j] = fmaf(av[i], bv[j], acc[i][j]);
        }
        __syncthreads();
    }

    // ---- epilogue ----
    int col0 = bn + tx * 4;
    if (col0 < N) {                  // N always multiple of 4 -> float4-safe
        float b0 = 0.f, b1 = 0.f, b2 = 0.f, b3 = 0.f;
        if (bias != nullptr) {
            b0 = bias[col0 + 0]; b1 = bias[col0 + 1];
            b2 = bias[col0 + 2]; b3 = bias[col0 + 3];
        }
        #pragma unroll
        for (int i = 0; i < 4; ++i) {
            long row = bm + ty * 4 + i;
            float4 o;
            o.x = acc[i][0] + b0;
            o.y = acc[i][1] + b1;
            o.z = acc[i][2] + b2;
            o.w = acc[i][3] + b3;
            if (EPI == 1) {
                o.x = geluf(o.x); o.y = geluf(o.y);
                o.z = geluf(o.z); o.w = geluf(o.w);
            }
            *(float4*)&C[row * (long)ldc + col0] = o;
        }
    }
}

// ---------------------------------------------------------------------------
// 4. causal depthwise conv (K=4) + bias + SiLU, IN PLACE in xz[..., :E]
// one thread per (b,e); register window over t
// ---------------------------------------------------------------------------
__global__ __launch_bounds__(256)
void conv_silu_kernel(float* __restrict__ xz,
                      const float* __restrict__ conv_w,
                      const float* __restrict__ conv_b,
                      int layer) {
    int g = blockIdx.x * blockDim.x + threadIdx.x;   // 0..B*E-1
    int b = g >> 9, e = g & (EE - 1);
    const float* w = conv_w + ((long)layer * EE + e) * KCONV;
    float w0 = w[0], w1 = w[1], w2 = w[2], w3 = w[3];
    float bias = conv_b[layer * EE + e];
    float x0 = 0.f, x1 = 0.f, x2 = 0.f;
    float* p = xz + (long)b * TT * (2 * EE) + e;
    for (int t = 0; t < TT; ++t) {
        float x3 = p[(long)t * (2 * EE)];
        float v = w0 * x0 + w1 * x1 + w2 * x2 + w3 * x3 + bias;
        p[(long)t * (2 * EE)] = siluf(v);
        x0 = x1; x1 = x2; x2 = x3;
    }
}

// ---------------------------------------------------------------------------
// 5. selective scan (dt projection + softplus folded in), y IN PLACE in
//    xz[..., :E].  one thread per (b,e), sequential over T.
// ---------------------------------------------------------------------------
__global__ __launch_bounds__(256)
void scan_kernel(const float* __restrict__ xdbl,
                 float* __restrict__ xz,          // xc half read/write
                 const float* __restrict__ dt_w,
                 const float* __restrict__ dt_b,
                 const float* __restrict__ A_log,
                 const float* __restrict__ Dp,
                 int layer) {
    int g = blockIdx.x * blockDim.x + threadIdx.x;   // 0..B*E-1
    int b = g >> 9, e = g & (EE - 1);
    float dw[RR];
    #pragma unroll
    for (int r = 0; r < RR; ++r) dw[r] = dt_w[((long)layer * EE + e) * RR + r];
    float db = dt_b[layer * EE + e];
    float Ar[NSTATE];
    #pragma unroll
    for (int n = 0; n < NSTATE; ++n)
        Ar[n] = -expf(A_log[((long)layer * EE + e) * NSTATE + n]);
    float Dv = Dp[layer * EE + e];

    float s[NSTATE];
    #pragma unroll
    for (int n = 0; n < NSTATE; ++n) s[n] = 0.f;

    const float* xd = xdbl + (long)b * TT * 48;
    float* xp = xz + (long)b * TT * (2 * EE) + e;

    for (int t = 0; t < TT; ++t) {
        const float* row = xd + t * 48;
        float rr = db;
        #pragma unroll
        for (int j = 0; j < RR; ++j) rr = fmaf(row[j], dw[j], rr);
        float dt = softplusf(rr);
        float x_t = xp[(long)t * (2 * EE)];
        float dx = dt * x_t;
        float acc = 0.f;
        #pragma unroll
        for (int n = 0; n < NSTATE; ++n) {
            s[n] = s[n] * expf(dt * Ar[n]) + dx * row[16 + n];
            acc = fmaf(s[n], row[32 + n], acc);
        }
        xp[(long)t * (2 * EE)] = acc + x_t * Dv;
    }
}

// ---------------------------------------------------------------------------
// 6. final gather: out[b,:] = h[b, clip(sl + sl/2 - 1, 0, T-1), :]
// ---------------------------------------------------------------------------
__global__ __launch_bounds__(256)
void gather_out_kernel(const float* __restrict__ h,
                       const int* __restrict__ seq_len,
                       float* __restrict__ out) {
    int b = blockIdx.x;
    int sl = seq_len[b];
    int tl = sl + sl / 2;
    int idx = tl - 1;
    if (idx < 0) idx = 0;
    if (idx > TT - 1) idx = TT - 1;
    out[(long)b * HH + threadIdx.x] = h[((long)b * TT + idx) * HH + threadIdx.x];
}

// ---------------------------------------------------------------------------
// launch
// ---------------------------------------------------------------------------
extern "C" void kernel_launch(void* const* d_in, const int* in_sizes, int n_in,
                              void* d_out, int out_size, void* d_ws, size_t ws_size,
                              hipStream_t stream) {
    const int*   item_seq  = (const int*)  d_in[0];
    const int*   seq_len   = (const int*)  d_in[1];
    const float* item_emb  = (const float*)d_in[2];
    const float* ln_w      = (const float*)d_in[3];
    const float* ln_b      = (const float*)d_in[4];
    const float* in_proj_w = (const float*)d_in[5];
    const float* conv_w    = (const float*)d_in[6];
    const float* conv_b    = (const float*)d_in[7];
    const float* x_proj_w  = (const float*)d_in[8];
    const float* dt_w      = (const float*)d_in[9];
    const float* dt_b      = (const float*)d_in[10];
    const float* A_log     = (const float*)d_in[11];
    const float* Dp        = (const float*)d_in[12];
    const float* out_w     = (const float*)d_in[13];
    const float* mn_w      = (const float*)d_in[14];
    const float* mn_b      = (const float*)d_in[15];
    const float* fc1_w     = (const float*)d_in[16];
    const float* fc1_b     = (const float*)d_in[17];
    const float* fc2_w     = (const float*)d_in[18];
    const float* fc2_b     = (const float*)d_in[19];
    const float* fn_w      = (const float*)d_in[20];
    const float* fn_b      = (const float*)d_in[21];

    float* ws   = (float*)d_ws;
    float* h    = ws;                                  // MTOK*H      = 19,660,800
    float* xz   = h    + (size_t)MTOK * HH;            // MTOK*2E     = 78,643,200
    float* xdbl = xz   + (size_t)MTOK * 2 * EE;        // MTOK*48     =  3,686,400
    float* tmp  = xdbl + (size_t)MTOK * 48;            // MTOK*H      = 19,660,800
    // total 121,651,200 floats = 486.6 MB

    // 1. embedding + LN
    embed_ln_kernel<<<MTOK, 256, 0, stream>>>(item_seq, item_emb, ln_w, ln_b, h);

    for (int l = 0; l < NLAYER; ++l) {
        // 2. in_proj: xz = h @ in_proj_w[l]^T   (M x 1024, K=256)
        {
            dim3 grid(MTOK / 64, (2 * EE) / 64);
            gemm_kernel<0, 0><<<grid, 256, 0, stream>>>(
                h, HH, nullptr, 0,
                in_proj_w + (size_t)l * 2 * EE * HH, nullptr,
                xz, 2 * EE, MTOK, 2 * EE, HH);
        }
        // 3. causal depthwise conv + SiLU (in place in xz[..., :E])
        conv_silu_kernel<<<(BB * EE) / 256, 256, 0, stream>>>(xz, conv_w, conv_b, l);
        // 4. x_proj: xdbl = xc @ x_proj_w[l]^T  (M x 48, K=512)
        {
            dim3 grid(MTOK / 64, 1);
            gemm_kernel<0, 0><<<grid, 256, 0, stream>>>(
                xz, 2 * EE, nullptr, 0,
                x_proj_w + (size_t)l * 48 * EE, nullptr,
                xdbl, 48, MTOK, 48, EE);
        }
        // 5. selective scan (y in place in xz[..., :E])
        scan_kernel<<<(BB * EE) / 256, 256, 0, stream>>>(
            xdbl, xz, dt_w, dt_b, A_log, Dp, l);
        // 6. out proj with fused y * silu(z):  tmp = (y*silu(z)) @ out_w[l]^T
        {
            dim3 grid(MTOK / 64, HH / 64);
            gemm_kernel<1, 0><<<grid, 256, 0, stream>>>(
                xz, 2 * EE, xz + EE, 2 * EE,
                out_w + (size_t)l * HH * EE, nullptr,
                tmp, HH, MTOK, HH, EE);
        }
        // 7. h = LN(tmp + h)
        add_ln_kernel<<<MTOK, 256, 0, stream>>>(tmp, h, mn_w + l * HH, mn_b + l * HH);
        // 8. fc1 + GELU: xz(ff) = gelu(h @ fc1_w^T + b)   (M x 1024, K=256)
        {
            dim3 grid(MTOK / 64, (4 * HH) / 64);
            gemm_kernel<0, 1><<<grid, 256, 0, stream>>>(
                h, HH, nullptr, 0,
                fc1_w + (size_t)l * 4 * HH * HH, fc1_b + (size_t)l * 4 * HH,
                xz, 4 * HH, MTOK, 4 * HH, HH);
        }
        // 9. fc2: tmp = ff @ fc2_w^T + b       (M x 256, K=1024)
        {
            dim3 grid(MTOK / 64, HH / 64);
            gemm_kernel<0, 0><<<grid, 256, 0, stream>>>(
                xz, 4 * HH, nullptr, 0,
                fc2_w + (size_t)l * HH * 4 * HH, fc2_b + (size_t)l * HH,
                tmp, HH, MTOK, HH, 4 * HH);
        }
        // 10. h = LN(tmp + h)
        add_ln_kernel<<<MTOK, 256, 0, stream>>>(tmp, h, fn_w + l * HH, fn_b + l * HH);
    }

    // 11. gather final position per batch
    gather_out_kernel<<<BB, 256, 0, stream>>>(h, seq_len, (float*)d_out);
}

// Round 3
// 3485.514 us; speedup vs baseline: 1.9060x; 1.9060x over previous
//
#include <hip/hip_runtime.h>
#include <math.h>

typedef unsigned short u16;
typedef __attribute__((ext_vector_type(8))) short bf8_t;   // 8 bf16 (4 VGPR)
typedef __attribute__((ext_vector_type(4))) float f4_t;    // 4 fp32

#define BB 256
#define LL 200
#define HH 256
#define EE 512
#define NSTATE 16
#define KCONV 4
#define RR 16
#define NLAYER 2
#define VV 150000
#define TT 300
#define MTOK (BB*TT)      // 76800

// ---------------------------------------------------------------------------
// helpers
// ---------------------------------------------------------------------------
__device__ __forceinline__ float siluf(float x) { return x / (1.0f + expf(-x)); }
__device__ __forceinline__ float geluf(float x) {
    return 0.5f * x * (1.0f + erff(x * 0.70710678118654752440f));
}
__device__ __forceinline__ u16 f2bf(float x) {               // RNE float->bf16
    unsigned u = __float_as_uint(x);
    unsigned r = u + 0x7FFF + ((u >> 16) & 1);
    return (u16)(r >> 16);
}
__device__ __forceinline__ float bf2f(u16 b) { return __uint_as_float((unsigned)b << 16); }

__device__ __forceinline__ void gload16(const void* gp, void* lp) {
    // async global->LDS, 16B per lane; lp must be wave-uniform (dest = lp + lane*16)
    __builtin_amdgcn_global_load_lds(
        (const __attribute__((address_space(1))) unsigned int*)gp,
        (__attribute__((address_space(3))) unsigned int*)lp,
        16, 0, 0);
}

__device__ __forceinline__ void block_reduce2(float& a, float& b) {
    __shared__ float ra[4], rb[4];
    #pragma unroll
    for (int o = 32; o > 0; o >>= 1) {
        a += __shfl_down(a, o, 64);
        b += __shfl_down(b, o, 64);
    }
    int lane = threadIdx.x & 63, w = threadIdx.x >> 6;
    if (lane == 0) { ra[w] = a; rb[w] = b; }
    __syncthreads();
    a = ra[0] + ra[1] + ra[2] + ra[3];
    b = rb[0] + rb[1] + rb[2] + rb[3];
}

// ---------------------------------------------------------------------------
// split a fp32 tensor into bf16 hi/lo planes (weights, per-GEMM)
// ---------------------------------------------------------------------------
__global__ __launch_bounds__(256)
void split_kernel(const float* __restrict__ x, u16* __restrict__ ph,
                  u16* __restrict__ pl, int n) {
    int i = blockIdx.x * 256 + threadIdx.x;
    if (i < n) {
        float v = x[i];
        u16 hb = f2bf(v);
        ph[i] = hb;
        pl[i] = f2bf(v - bf2f(hb));
    }
}

// ---------------------------------------------------------------------------
// 1. embedding gather (with interleave) + LayerNorm -> hi/lo planes of h
// ---------------------------------------------------------------------------
__global__ __launch_bounds__(256)
void embed_ln_kernel(const int* __restrict__ item_seq,
                     const float* __restrict__ item_emb,
                     const float* __restrict__ ln_w,
                     const float* __restrict__ ln_b,
                     u16* __restrict__ hh, u16* __restrict__ hl) {
    int tok = blockIdx.x;
    int b = tok / TT, p = tok - b * TT;
    int k = p / 3, r = p - 3 * k;
    int item;
    if (r == 2) item = VV - 1;
    else        item = item_seq[b * LL + 2 * k + r];
    int tid = threadIdx.x;
    float x = item_emb[(size_t)item * HH + tid];
    float s1 = x, s2 = x * x;
    block_reduce2(s1, s2);
    float m = s1 * (1.0f / HH);
    float var = s2 * (1.0f / HH) - m * m;
    float inv = rsqrtf(var + 1e-12f);
    float v = (x - m) * inv * ln_w[tid] + ln_b[tid];
    size_t idx = (size_t)tok * HH + tid;
    u16 hb = f2bf(v);
    hh[idx] = hb;
    hl[idx] = f2bf(v - bf2f(hb));
}

// ---------------------------------------------------------------------------
// 2. residual add + LayerNorm on the hi/lo plane residual stream
// ---------------------------------------------------------------------------
__global__ __launch_bounds__(256)
void add_ln_kernel(const float* __restrict__ tmp,
                   u16* __restrict__ hh, u16* __restrict__ hl,
                   const float* __restrict__ w,
                   const float* __restrict__ bnorm) {
    int tok = blockIdx.x;
    int tid = threadIdx.x;
    size_t idx = (size_t)tok * HH + tid;
    float x = tmp[idx] + bf2f(hh[idx]) + bf2f(hl[idx]);
    float s1 = x, s2 = x * x;
    block_reduce2(s1, s2);
    float m = s1 * (1.0f / HH);
    float var = s2 * (1.0f / HH) - m * m;
    float inv = rsqrtf(var + 1e-12f);
    float v = (x - m) * inv * w[tid] + bnorm[tid];
    u16 hb = f2bf(v);
    hh[idx] = hb;
    hl[idx] = f2bf(v - bf2f(hb));
}

// ---------------------------------------------------------------------------
// 3. split-bf16 MFMA GEMM: C[M,N] = A[M,K] @ W[N,K]^T (+bias)
//    3 MFMAs per fragment pair: Ah*Wh + Ah*Wl + Al*Wh  (~fp32 precision)
//    128x128 tile, BK=32, 256 threads = 4 waves (2x2 of 64x64).
//    AMODE 0: A = bf16 hi/lo planes (lda=K), staged via global_load_lds
//    AMODE 1: A = fp32 xz rows (lda=2E): u = y*silu(z), split in regs, ds_write
//    MODE 0: fp32 C (+bias if non-null).  MODE 1: gelu(C+bias) -> hi/lo planes
// ---------------------------------------------------------------------------
template <int AMODE, int MODE>
__global__ __launch_bounds__(256)
void gemm_mfma(const u16* __restrict__ Ah, const u16* __restrict__ Al,
               const float* __restrict__ Af,
               const u16* __restrict__ Wh, const u16* __restrict__ Wl,
               const float* __restrict__ bias,
               float* __restrict__ C,
               u16* __restrict__ Ch, u16* __restrict__ Cl,
               int M, int N, int K) {
    __shared__ u16 sA[2][128 * 32];   // [hi/lo][row*32+k]  8KB each
    __shared__ u16 sB[2][128 * 32];
    int tid = threadIdx.x;
    int lane = tid & 63, wid = tid >> 6;
    int wr = wid >> 1, wc = wid & 1;
    int bn = blockIdx.x * 128;        // grid.x = N/128: co-resident blocks share A panel
    int bm = blockIdx.y * 128;

    f4_t acc[4][4];
    #pragma unroll
    for (int i = 0; i < 4; ++i)
        #pragma unroll
        for (int j = 0; j < 4; ++j)
            acc[i][j] = (f4_t){0.f, 0.f, 0.f, 0.f};

    int scol = (lane & 3) * 8;        // k-col (u16) of this lane's 16B chunk

    for (int k0 = 0; k0 < K; k0 += 32) {
        // ---- stage A ----
        if (AMODE == 0) {
            #pragma unroll
            for (int q = 0; q < 2; ++q) {
                int row = wid * 32 + q * 16 + (lane >> 2);
                size_t ga = (size_t)(bm + row) * K + k0 + scol;
                int off = (wid * 2 + q) * 1024;   // bytes
                gload16(Ah + ga, (char*)&sA[0][0] + off);
                gload16(Al + ga, (char*)&sA[1][0] + off);
            }
        } else {
            // reg-staged: u = y * silu(z) from fp32 xz rows
            int r = tid >> 1;                 // 0..127
            int kc = (tid & 1) * 16;          // 0 or 16
            size_t base = (size_t)(bm + r) * (2 * EE) + k0 + kc;
            float us[16];
            #pragma unroll
            for (int i = 0; i < 16; i += 4) {
                float4 y4 = *(const float4*)(Af + base + i);
                float4 z4 = *(const float4*)(Af + base + EE + i);
                us[i + 0] = y4.x * (z4.x / (1.f + __expf(-z4.x)));
                us[i + 1] = y4.y * (z4.y / (1.f + __expf(-z4.y)));
                us[i + 2] = y4.z * (z4.z / (1.f + __expf(-z4.z)));
                us[i + 3] = y4.w * (z4.w / (1.f + __expf(-z4.w)));
            }
            alignas(16) u16 hb[16], lb[16];
            #pragma unroll
            for (int i = 0; i < 16; ++i) {
                hb[i] = f2bf(us[i]);
                lb[i] = f2bf(us[i] - bf2f(hb[i]));
            }
            *(bf8_t*)&sA[0][r * 32 + kc]     = *(bf8_t*)&hb[0];
            *(bf8_t*)&sA[0][r * 32 + kc + 8] = *(bf8_t*)&hb[8];
            *(bf8_t*)&sA[1][r * 32 + kc]     = *(bf8_t*)&lb[0];
            *(bf8_t*)&sA[1][r * 32 + kc + 8] = *(bf8_t*)&lb[8];
        }
        // ---- stage W ----
        #pragma unroll
        for (int q = 0; q < 2; ++q) {
            int row = wid * 32 + q * 16 + (lane >> 2);
            size_t gb = (size_t)(bn + row) * K + k0 + scol;
            int off = (wid * 2 + q) * 1024;
            gload16(Wh + gb, (char*)&sB[0][0] + off);
            gload16(Wl + gb, (char*)&sB[1][0] + off);
        }
        __syncthreads();

        int arow = wr * 64 + (lane & 15);
        int koff = (lane >> 4) * 8;
        bf8_t ah[4], al[4];
        #pragma unroll
        for (int fm = 0; fm < 4; ++fm) {
            int r = arow + fm * 16;
            ah[fm] = *(const bf8_t*)&sA[0][r * 32 + koff];
            al[fm] = *(const bf8_t*)&sA[1][r * 32 + koff];
        }
        #pragma unroll
        for (int fn = 0; fn < 4; ++fn) {
            int r = wc * 64 + fn * 16 + (lane & 15);
            bf8_t bh = *(const bf8_t*)&sB[0][r * 32 + koff];
            bf8_t bl = *(const bf8_t*)&sB[1][r * 32 + koff];
            #pragma unroll
            for (int fm = 0; fm < 4; ++fm) {
                acc[fm][fn] = __builtin_amdgcn_mfma_f32_16x16x32_bf16(ah[fm], bh, acc[fm][fn], 0, 0, 0);
                acc[fm][fn] = __builtin_amdgcn_mfma_f32_16x16x32_bf16(ah[fm], bl, acc[fm][fn], 0, 0, 0);
                acc[fm][fn] = __builtin_amdgcn_mfma_f32_16x16x32_bf16(al[fm], bh, acc[fm][fn], 0, 0, 0);
            }
        }
        __syncthreads();
    }

    // epilogue: C/D layout col = lane&15, row = (lane>>4)*4 + j   [m89]
    #pragma unroll
    for (int fn = 0; fn < 4; ++fn) {
        int colg = bn + wc * 64 + fn * 16 + (lane & 15);
        float bv = (bias != nullptr) ? bias[colg] : 0.f;
        #pragma unroll
        for (int fm = 0; fm < 4; ++fm) {
            #pragma unroll
            for (int j = 0; j < 4; ++j) {
                int rowg = bm + wr * 64 + fm * 16 + (lane >> 4) * 4 + j;
                float v = acc[fm][fn][j] + bv;
                if (MODE == 0) {
                    C[(size_t)rowg * N + colg] = v;
                } else {
                    v = geluf(v);
                    u16 hbv = f2bf(v);
                    Ch[(size_t)rowg * N + colg] = hbv;
                    Cl[(size_t)rowg * N + colg] = f2bf(v - bf2f(hbv));
                }
            }
        }
    }
}

// ---------------------------------------------------------------------------
// 4. small fp32 GEMM for x_proj (N=48): 64x64 tile, BK=16
// ---------------------------------------------------------------------------
__global__ __launch_bounds__(256)
void gemm64_kernel(const float* __restrict__ A, int lda,
                   const float* __restrict__ W,
                   float* __restrict__ C, int ldc,
                   int M, int N, int Kd) {
    __shared__ float As[16][64];
    __shared__ float Bs[16][64];
    int bm = blockIdx.x * 64;
    int tid = threadIdx.x;
    int tx = tid & 15, ty = tid >> 4;
    int lrow = tid >> 2;
    int lcol = (tid & 3) * 4;

    float acc[4][4] = {{0.f}};
    for (int k0 = 0; k0 < Kd; k0 += 16) {
        {
            size_t gr = bm + lrow;
            float4 a4 = *(const float4*)(A + gr * (size_t)lda + k0 + lcol);
            As[lcol + 0][lrow] = a4.x; As[lcol + 1][lrow] = a4.y;
            As[lcol + 2][lrow] = a4.z; As[lcol + 3][lrow] = a4.w;
        }
        {
            int gr = lrow;
            float4 b4 = make_float4(0.f, 0.f, 0.f, 0.f);
            if (gr < N) b4 = *(const float4*)(W + (size_t)gr * Kd + k0 + lcol);
            Bs[lcol + 0][lrow] = b4.x; Bs[lcol + 1][lrow] = b4.y;
            Bs[lcol + 2][lrow] = b4.z; Bs[lcol + 3][lrow] = b4.w;
        }
        __syncthreads();
        #pragma unroll
        for (int kk = 0; kk < 16; ++kk) {
            float4 a4 = *(const float4*)&As[kk][ty * 4];
            float4 b4 = *(const float4*)&Bs[kk][tx * 4];
            float av[4] = {a4.x, a4.y, a4.z, a4.w};
            float bv[4] = {b4.x, b4.y, b4.z, b4.w};
            #pragma unroll
            for (int i = 0; i < 4; ++i)
                #pragma unroll
                for (int j = 0; j < 4; ++j)
                    acc[i][j] = fmaf(av[i], bv[j], acc[i][j]);
        }
        __syncthreads();
    }
    int col0 = tx * 4;
    if (col0 < N) {
        #pragma unroll
        for (int i = 0; i < 4; ++i) {
            size_t row = bm + ty * 4 + i;
            float4 o = make_float4(acc[i][0], acc[i][1], acc[i][2], acc[i][3]);
            *(float4*)&C[row * (size_t)ldc + col0] = o;
        }
    }
}

// ---------------------------------------------------------------------------
// 5. causal depthwise conv (K=4) + bias + SiLU, in place in xz[..., :E]
// ---------------------------------------------------------------------------
__global__ __launch_bounds__(256)
void conv_silu_kernel(float* __restrict__ xz,
                      const float* __restrict__ conv_w,
                      const float* __restrict__ conv_b,
                      int layer) {
    int g = blockIdx.x * blockDim.x + threadIdx.x;
    int b = g >> 9, e = g & (EE - 1);
    const float* w = conv_w + ((size_t)layer * EE + e) * KCONV;
    float w0 = w[0], w1 = w[1], w2 = w[2], w3 = w[3];
    float bias = conv_b[layer * EE + e];
    float x0 = 0.f, x1 = 0.f, x2 = 0.f;
    float* p = xz + (size_t)b * TT * (2 * EE) + e;
    for (int t = 0; t < TT; ++t) {
        float x3 = p[(size_t)t * (2 * EE)];
        float v = w0 * x0 + w1 * x1 + w2 * x2 + w3 * x3 + bias;
        p[(size_t)t * (2 * EE)] = siluf(v);
        x0 = x1; x1 = x2; x2 = x3;
    }
}

// ---------------------------------------------------------------------------
// 6. selective scan, 4-way state split (thread = (b,e,n-group of 4)).
//    dt-projection + softplus folded in.  y written IN PLACE into xc slot.
// ---------------------------------------------------------------------------
__global__ __launch_bounds__(256)
void scan_kernel(const float* __restrict__ xdbl,
                 float* __restrict__ xz,
                 const float* __restrict__ dt_w,
                 const float* __restrict__ dt_b,
                 const float* __restrict__ A_log,
                 const float* __restrict__ Dp,
                 int layer) {
    int g = blockIdx.x * 256 + threadIdx.x;    // 0 .. B*E*4-1
    int sub = g & 3;
    int idx = g >> 2;
    int e = idx & (EE - 1), b = idx >> 9;
    int ns = sub * 4;

    const float* dwp = dt_w + ((size_t)layer * EE + e) * RR + ns;
    float dw0 = dwp[0], dw1 = dwp[1], dw2 = dwp[2], dw3 = dwp[3];
    float db = dt_b[layer * EE + e];
    float Ar[4];
    #pragma unroll
    for (int n = 0; n < 4; ++n)
        Ar[n] = -expf(A_log[((size_t)layer * EE + e) * NSTATE + ns + n]);
    float Dv = Dp[layer * EE + e];

    float s[4] = {0.f, 0.f, 0.f, 0.f};
    const float* xd = xdbl + (size_t)b * TT * 48;
    float* xp = xz + (size_t)b * TT * (2 * EE) + e;

    for (int t = 0; t < TT; ++t) {
        const float* row = xd + t * 48;
        float rr = row[ns] * dw0 + row[ns + 1] * dw1 + row[ns + 2] * dw2 + row[ns + 3] * dw3;
        rr += __shfl_xor(rr, 1);
        rr += __shfl_xor(rr, 2);
        rr += db;
        float dt = fmaxf(rr, 0.f) + log1pf(__expf(-fabsf(rr)));
        float x_t = xp[(size_t)t * (2 * EE)];
        float dx = dt * x_t;
        float acc = 0.f;
        #pragma unroll
        for (int n = 0; n < 4; ++n) {
            float es = __expf(dt * Ar[n]);
            s[n] = fmaf(s[n], es, dx * row[16 + ns + n]);
            acc = fmaf(s[n], row[32 + ns + n], acc);
        }
        acc += __shfl_xor(acc, 1);
        acc += __shfl_xor(acc, 2);
        if (sub == 0) xp[(size_t)t * (2 * EE)] = acc + x_t * Dv;
    }
}

// ---------------------------------------------------------------------------
// 7. final gather (reconstruct from planes)
// ---------------------------------------------------------------------------
__global__ __launch_bounds__(256)
void gather_out_kernel(const u16* __restrict__ hh, const u16* __restrict__ hl,
                       const int* __restrict__ seq_len,
                       float* __restrict__ out) {
    int b = blockIdx.x;
    int sl = seq_len[b];
    int tl = sl + sl / 2;
    int idx = tl - 1;
    if (idx < 0) idx = 0;
    if (idx > TT - 1) idx = TT - 1;
    size_t src = ((size_t)b * TT + idx) * HH + threadIdx.x;
    out[(size_t)b * HH + threadIdx.x] = bf2f(hh[src]) + bf2f(hl[src]);
}

// ---------------------------------------------------------------------------
// launch
// ---------------------------------------------------------------------------
extern "C" void kernel_launch(void* const* d_in, const int* in_sizes, int n_in,
                              void* d_out, int out_size, void* d_ws, size_t ws_size,
                              hipStream_t stream) {
    const int*   item_seq  = (const int*)  d_in[0];
    const int*   seq_len   = (const int*)  d_in[1];
    const float* item_emb  = (const float*)d_in[2];
    const float* ln_w      = (const float*)d_in[3];
    const float* ln_b      = (const float*)d_in[4];
    const float* in_proj_w = (const float*)d_in[5];
    const float* conv_w    = (const float*)d_in[6];
    const float* conv_b    = (const float*)d_in[7];
    const float* x_proj_w  = (const float*)d_in[8];
    const float* dt_w      = (const float*)d_in[9];
    const float* dt_b      = (const float*)d_in[10];
    const float* A_log     = (const float*)d_in[11];
    const float* Dp        = (const float*)d_in[12];
    const float* out_w     = (const float*)d_in[13];
    const float* mn_w      = (const float*)d_in[14];
    const float* mn_b      = (const float*)d_in[15];
    const float* fc1_w     = (const float*)d_in[16];
    const float* fc1_b     = (const float*)d_in[17];
    const float* fc2_w     = (const float*)d_in[18];
    const float* fc2_b     = (const float*)d_in[19];
    const float* fn_w      = (const float*)d_in[20];
    const float* fn_b      = (const float*)d_in[21];

    // ---- workspace layout: EXACTLY 486,604,800 B (== round-1 proven size) ----
    float* xz   = (float*)d_ws;                       // MTOK*2E f   = 314,572,800 B
    u16*   hh   = (u16*)(xz + (size_t)MTOK * 2 * EE); // MTOK*H u16  =  39,321,600 B
    u16*   hl   = hh + (size_t)MTOK * HH;             //                39,321,600 B
    float* tmp  = (float*)(hl + (size_t)MTOK * HH);   // MTOK*H f    =  78,643,200 B
    float* xdbl = tmp + (size_t)MTOK * HH;            // MTOK*48 f   =  14,745,600 B
    // rotating weight-plane scratch ALIASES xdbl (live ranges disjoint):
    u16* wsH = (u16*)xdbl;                            // <=262,144 u16
    u16* wsL = wsH + 262144;
    // fc1 output planes alias xz (xc/z dead by then):
    u16* ffh = (u16*)xz;                              // MTOK*4H u16 = 157,286,400 B
    u16* ffl = ffh + (size_t)MTOK * 4 * HH;           //              157,286,400 B

    // 1. embedding + LN -> h planes
    embed_ln_kernel<<<MTOK, 256, 0, stream>>>(item_seq, item_emb, ln_w, ln_b, hh, hl);

    for (int l = 0; l < NLAYER; ++l) {
        // 2. in_proj: xz = h @ in_proj_w[l]^T   (M x 1024, K=256)
        {
            int nw = 2 * EE * HH;   // 262,144 (xdbl is dead here)
            split_kernel<<<nw / 256, 256, 0, stream>>>(
                in_proj_w + (size_t)l * nw, wsH, wsL, nw);
            dim3 grid((2 * EE) / 128, MTOK / 128);
            gemm_mfma<0, 0><<<grid, 256, 0, stream>>>(
                hh, hl, nullptr, wsH, wsL,
                nullptr, xz, nullptr, nullptr, MTOK, 2 * EE, HH);
        }
        // 3. causal depthwise conv + SiLU (in place in xc)
        conv_silu_kernel<<<(BB * EE) / 256, 256, 0, stream>>>(xz, conv_w, conv_b, l);
        // 4. x_proj: xdbl = xc @ x_proj_w[l]^T  (M x 48, K=512) — overwrites scratch
        gemm64_kernel<<<MTOK / 64, 256, 0, stream>>>(
            xz, 2 * EE, x_proj_w + (size_t)l * 48 * EE, xdbl, 48, MTOK, 48, EE);
        // 5. selective scan: y in place in xc
        scan_kernel<<<(BB * EE * 4) / 256, 256, 0, stream>>>(
            xdbl, xz, dt_w, dt_b, A_log, Dp, l);
        // 6. out proj: tmp = (y*silu(z)) @ out_w[l]^T   (M x 256, K=512)
        {
            int nw = HH * EE;       // 131,072 (xdbl dead after scan)
            split_kernel<<<nw / 256, 256, 0, stream>>>(
                out_w + (size_t)l * nw, wsH, wsL, nw);
            dim3 grid(HH / 128, MTOK / 128);
            gemm_mfma<1, 0><<<grid, 256, 0, stream>>>(
                nullptr, nullptr, xz, wsH, wsL,
                nullptr, tmp, nullptr, nullptr, MTOK, HH, EE);
        }
        // 7. h = LN(tmp + h)
        add_ln_kernel<<<MTOK, 256, 0, stream>>>(tmp, hh, hl, mn_w + l * HH, mn_b + l * HH);
        // 8. fc1 + GELU -> ff planes (alias xz)   (M x 1024, K=256)
        {
            int nw = 4 * HH * HH;   // 262,144
            split_kernel<<<nw / 256, 256, 0, stream>>>(
                fc1_w + (size_t)l * nw, wsH, wsL, nw);
            dim3 grid((4 * HH) / 128, MTOK / 128);
            gemm_mfma<0, 1><<<grid, 256, 0, stream>>>(
                hh, hl, nullptr, wsH, wsL,
                fc1_b + (size_t)l * 4 * HH,
                nullptr, ffh, ffl, MTOK, 4 * HH, HH);
        }
        // 9. fc2: tmp = ff @ fc2_w^T + b          (M x 256, K=1024)
        {
            int nw = HH * 4 * HH;   // 262,144
            split_kernel<<<nw / 256, 256, 0, stream>>>(
                fc2_w + (size_t)l * nw, wsH, wsL, nw);
            dim3 grid(HH / 128, MTOK / 128);
            gemm_mfma<0, 0><<<grid, 256, 0, stream>>>(
                ffh, ffl, nullptr, wsH, wsL,
                fc2_b + (size_t)l * HH,
                tmp, nullptr, nullptr, MTOK, HH, 4 * HH);
        }
        // 10. h = LN(tmp + h)
        add_ln_kernel<<<MTOK, 256, 0, stream>>>(tmp, hh, hl, fn_w + l * HH, fn_b + l * HH);
    }

    // 11. gather final position per batch
    gather_out_kernel<<<BB, 256, 0, stream>>>(hh, hl, seq_len, (float*)d_out);
}

// Round 4
// 2932.520 us; speedup vs baseline: 2.2654x; 1.1886x over previous
//
#include <hip/hip_runtime.h>
#include <math.h>

typedef unsigned short u16;
typedef __attribute__((ext_vector_type(8))) short bf8_t;   // 8 bf16 (4 VGPR)
typedef __attribute__((ext_vector_type(4))) float f4_t;    // 4 fp32

#define BB 256
#define LL 200
#define HH 256
#define EE 512
#define NSTATE 16
#define KCONV 4
#define RR 16
#define NLAYER 2
#define VV 150000
#define TT 300
#define MTOK (BB*TT)      // 76800

// ---------------------------------------------------------------------------
// helpers
// ---------------------------------------------------------------------------
__device__ __forceinline__ float siluf(float x) { return x / (1.0f + expf(-x)); }
__device__ __forceinline__ float geluf(float x) {
    return 0.5f * x * (1.0f + erff(x * 0.70710678118654752440f));
}
__device__ __forceinline__ u16 f2bf(float x) {               // RNE float->bf16
    unsigned u = __float_as_uint(x);
    unsigned r = u + 0x7FFF + ((u >> 16) & 1);
    return (u16)(r >> 16);
}
__device__ __forceinline__ float bf2f(u16 b) { return __uint_as_float((unsigned)b << 16); }

__device__ __forceinline__ void gload16(const void* gp, void* lp) {
    // async global->LDS, 16B per lane; lp must be wave-uniform (dest = lp + lane*16)
    __builtin_amdgcn_global_load_lds(
        (const __attribute__((address_space(1))) unsigned int*)gp,
        (__attribute__((address_space(3))) unsigned int*)lp,
        16, 0, 0);
}

__device__ __forceinline__ void block_reduce2(float& a, float& b) {
    __shared__ float ra[4], rb[4];
    #pragma unroll
    for (int o = 32; o > 0; o >>= 1) {
        a += __shfl_down(a, o, 64);
        b += __shfl_down(b, o, 64);
    }
    int lane = threadIdx.x & 63, w = threadIdx.x >> 6;
    if (lane == 0) { ra[w] = a; rb[w] = b; }
    __syncthreads();
    a = ra[0] + ra[1] + ra[2] + ra[3];
    b = rb[0] + rb[1] + rb[2] + rb[3];
}

// ---------------------------------------------------------------------------
// split a fp32 tensor into bf16 hi/lo planes (weights, per-GEMM)
// ---------------------------------------------------------------------------
__global__ __launch_bounds__(256)
void split_kernel(const float* __restrict__ x, u16* __restrict__ ph,
                  u16* __restrict__ pl, int n) {
    int i = blockIdx.x * 256 + threadIdx.x;
    if (i < n) {
        float v = x[i];
        u16 hb = f2bf(v);
        ph[i] = hb;
        pl[i] = f2bf(v - bf2f(hb));
    }
}

// ---------------------------------------------------------------------------
// 1. embedding gather (with interleave) + LayerNorm -> hi/lo planes of h
// ---------------------------------------------------------------------------
__global__ __launch_bounds__(256)
void embed_ln_kernel(const int* __restrict__ item_seq,
                     const float* __restrict__ item_emb,
                     const float* __restrict__ ln_w,
                     const float* __restrict__ ln_b,
                     u16* __restrict__ hh, u16* __restrict__ hl) {
    int tok = blockIdx.x;
    int b = tok / TT, p = tok - b * TT;
    int k = p / 3, r = p - 3 * k;
    int item;
    if (r == 2) item = VV - 1;
    else        item = item_seq[b * LL + 2 * k + r];
    int tid = threadIdx.x;
    float x = item_emb[(size_t)item * HH + tid];
    float s1 = x, s2 = x * x;
    block_reduce2(s1, s2);
    float m = s1 * (1.0f / HH);
    float var = s2 * (1.0f / HH) - m * m;
    float inv = rsqrtf(var + 1e-12f);
    float v = (x - m) * inv * ln_w[tid] + ln_b[tid];
    size_t idx = (size_t)tok * HH + tid;
    u16 hb = f2bf(v);
    hh[idx] = hb;
    hl[idx] = f2bf(v - bf2f(hb));
}

// ---------------------------------------------------------------------------
// 2. residual add + LayerNorm on the hi/lo plane residual stream
// ---------------------------------------------------------------------------
__global__ __launch_bounds__(256)
void add_ln_kernel(const float* __restrict__ tmp,
                   u16* __restrict__ hh, u16* __restrict__ hl,
                   const float* __restrict__ w,
                   const float* __restrict__ bnorm) {
    int tok = blockIdx.x;
    int tid = threadIdx.x;
    size_t idx = (size_t)tok * HH + tid;
    float x = tmp[idx] + bf2f(hh[idx]) + bf2f(hl[idx]);
    float s1 = x, s2 = x * x;
    block_reduce2(s1, s2);
    float m = s1 * (1.0f / HH);
    float var = s2 * (1.0f / HH) - m * m;
    float inv = rsqrtf(var + 1e-12f);
    float v = (x - m) * inv * w[tid] + bnorm[tid];
    u16 hb = f2bf(v);
    hh[idx] = hb;
    hl[idx] = f2bf(v - bf2f(hb));
}

// ---------------------------------------------------------------------------
// 3. split-bf16 MFMA GEMM: C[M,N] = A[M,K] @ W[N,K]^T (+bias)
//    3 MFMAs per fragment pair: Ah*Wh + Ah*Wl + Al*Wh  (~fp32 precision)
//    128x128 tile, BK=32, 256 threads = 4 waves (2x2 of 64x64).
//    AMODE 0: A = bf16 hi/lo planes (lda=K), staged via global_load_lds
//    AMODE 1: A = fp32 rows (lda=ldaf): u = y*silu(z at +EE), reg split
//    AMODE 2: A = fp32 rows (lda=ldaf): plain, reg split
//    MODE 0: fp32 C (+bias if non-null).  MODE 1: gelu(C+bias) -> hi/lo planes
//    Epilogue col-guarded (N may be < tile, e.g. 48).
//    XCD-aware bijective block swizzle (m204) for A-panel L2 reuse.
// ---------------------------------------------------------------------------
template <int AMODE, int MODE>
__global__ __launch_bounds__(256)
void gemm_mfma(const u16* __restrict__ Ah, const u16* __restrict__ Al,
               const float* __restrict__ Af, int ldaf,
               const u16* __restrict__ Wh, const u16* __restrict__ Wl,
               const float* __restrict__ bias,
               float* __restrict__ C,
               u16* __restrict__ Ch, u16* __restrict__ Cl,
               int M, int N, int K) {
    __shared__ u16 sA[2][128 * 32];   // [hi/lo][row*32+k]  8KB each
    __shared__ u16 sB[2][128 * 32];
    int tid = threadIdx.x;
    int lane = tid & 63, wid = tid >> 6;
    int wr = wid >> 1, wc = wid & 1;

    // XCD-aware bijective swizzle of the linear block id (m204)
    int gx = gridDim.x, nwg = gx * gridDim.y;
    int id = blockIdx.y * gx + blockIdx.x;
    int q = nwg >> 3, rr8 = nwg & 7;
    int xcd = id & 7, pos = id >> 3;
    int nid = (xcd < rr8 ? xcd * (q + 1) : rr8 * (q + 1) + (xcd - rr8) * q) + pos;
    int bn = (nid % gx) * 128;        // grid.x = N/128
    int bm = (nid / gx) * 128;

    f4_t acc[4][4];
    #pragma unroll
    for (int i = 0; i < 4; ++i)
        #pragma unroll
        for (int j = 0; j < 4; ++j)
            acc[i][j] = (f4_t){0.f, 0.f, 0.f, 0.f};

    int scol = (lane & 3) * 8;        // k-col (u16) of this lane's 16B chunk

    for (int k0 = 0; k0 < K; k0 += 32) {
        // ---- stage A ----
        if (AMODE == 0) {
            #pragma unroll
            for (int qq = 0; qq < 2; ++qq) {
                int row = wid * 32 + qq * 16 + (lane >> 2);
                size_t ga = (size_t)(bm + row) * K + k0 + scol;
                int off = (wid * 2 + qq) * 1024;   // bytes
                gload16(Ah + ga, (char*)&sA[0][0] + off);
                gload16(Al + ga, (char*)&sA[1][0] + off);
            }
        } else {
            // reg-staged from fp32 rows
            int r = tid >> 1;                 // 0..127
            int kc = (tid & 1) * 16;          // 0 or 16
            size_t base = (size_t)(bm + r) * ldaf + k0 + kc;
            float us[16];
            #pragma unroll
            for (int i = 0; i < 16; i += 4) {
                float4 y4 = *(const float4*)(Af + base + i);
                if (AMODE == 1) {
                    float4 z4 = *(const float4*)(Af + base + EE + i);
                    us[i + 0] = y4.x * (z4.x / (1.f + __expf(-z4.x)));
                    us[i + 1] = y4.y * (z4.y / (1.f + __expf(-z4.y)));
                    us[i + 2] = y4.z * (z4.z / (1.f + __expf(-z4.z)));
                    us[i + 3] = y4.w * (z4.w / (1.f + __expf(-z4.w)));
                } else {
                    us[i + 0] = y4.x; us[i + 1] = y4.y;
                    us[i + 2] = y4.z; us[i + 3] = y4.w;
                }
            }
            alignas(16) u16 hb[16], lb[16];
            #pragma unroll
            for (int i = 0; i < 16; ++i) {
                hb[i] = f2bf(us[i]);
                lb[i] = f2bf(us[i] - bf2f(hb[i]));
            }
            *(bf8_t*)&sA[0][r * 32 + kc]     = *(bf8_t*)&hb[0];
            *(bf8_t*)&sA[0][r * 32 + kc + 8] = *(bf8_t*)&hb[8];
            *(bf8_t*)&sA[1][r * 32 + kc]     = *(bf8_t*)&lb[0];
            *(bf8_t*)&sA[1][r * 32 + kc + 8] = *(bf8_t*)&lb[8];
        }
        // ---- stage W ----
        #pragma unroll
        for (int qq = 0; qq < 2; ++qq) {
            int row = wid * 32 + qq * 16 + (lane >> 2);
            size_t gb = (size_t)(bn + row) * K + k0 + scol;
            int off = (wid * 2 + qq) * 1024;
            gload16(Wh + gb, (char*)&sB[0][0] + off);
            gload16(Wl + gb, (char*)&sB[1][0] + off);
        }
        __syncthreads();

        int arow = wr * 64 + (lane & 15);
        int koff = (lane >> 4) * 8;
        bf8_t ah[4], al[4];
        #pragma unroll
        for (int fm = 0; fm < 4; ++fm) {
            int r = arow + fm * 16;
            ah[fm] = *(const bf8_t*)&sA[0][r * 32 + koff];
            al[fm] = *(const bf8_t*)&sA[1][r * 32 + koff];
        }
        #pragma unroll
        for (int fn = 0; fn < 4; ++fn) {
            int r = wc * 64 + fn * 16 + (lane & 15);
            bf8_t bh = *(const bf8_t*)&sB[0][r * 32 + koff];
            bf8_t bl = *(const bf8_t*)&sB[1][r * 32 + koff];
            #pragma unroll
            for (int fm = 0; fm < 4; ++fm) {
                acc[fm][fn] = __builtin_amdgcn_mfma_f32_16x16x32_bf16(ah[fm], bh, acc[fm][fn], 0, 0, 0);
                acc[fm][fn] = __builtin_amdgcn_mfma_f32_16x16x32_bf16(ah[fm], bl, acc[fm][fn], 0, 0, 0);
                acc[fm][fn] = __builtin_amdgcn_mfma_f32_16x16x32_bf16(al[fm], bh, acc[fm][fn], 0, 0, 0);
            }
        }
        __syncthreads();
    }

    // epilogue: C/D layout col = lane&15, row = (lane>>4)*4 + j   [m89]
    #pragma unroll
    for (int fn = 0; fn < 4; ++fn) {
        int colg = bn + wc * 64 + fn * 16 + (lane & 15);
        if (colg < N) {
            float bv = (bias != nullptr) ? bias[colg] : 0.f;
            #pragma unroll
            for (int fm = 0; fm < 4; ++fm) {
                #pragma unroll
                for (int j = 0; j < 4; ++j) {
                    int rowg = bm + wr * 64 + fm * 16 + (lane >> 4) * 4 + j;
                    float v = acc[fm][fn][j] + bv;
                    if (MODE == 0) {
                        C[(size_t)rowg * N + colg] = v;
                    } else {
                        v = geluf(v);
                        u16 hbv = f2bf(v);
                        Ch[(size_t)rowg * N + colg] = hbv;
                        Cl[(size_t)rowg * N + colg] = f2bf(v - bf2f(hbv));
                    }
                }
            }
        }
    }
}

// ---------------------------------------------------------------------------
// 4. causal depthwise conv (K=4) + bias + SiLU, in place in xz[..., :E]
// ---------------------------------------------------------------------------
__global__ __launch_bounds__(256)
void conv_silu_kernel(float* __restrict__ xz,
                      const float* __restrict__ conv_w,
                      const float* __restrict__ conv_b,
                      int layer) {
    int g = blockIdx.x * blockDim.x + threadIdx.x;
    int b = g >> 9, e = g & (EE - 1);
    const float* w = conv_w + ((size_t)layer * EE + e) * KCONV;
    float w0 = w[0], w1 = w[1], w2 = w[2], w3 = w[3];
    float bias = conv_b[layer * EE + e];
    float x0 = 0.f, x1 = 0.f, x2 = 0.f;
    float* p = xz + (size_t)b * TT * (2 * EE) + e;
    for (int t = 0; t < TT; ++t) {
        float x3 = p[(size_t)t * (2 * EE)];
        float v = w0 * x0 + w1 * x1 + w2 * x2 + w3 * x3 + bias;
        p[(size_t)t * (2 * EE)] = siluf(v);
        x0 = x1; x1 = x2; x2 = x3;
    }
}

// ---------------------------------------------------------------------------
// 5. selective scan v3: ONE thread per (b,e), all 16 states in registers.
//    No cross-lane ops.  dt-projection + softplus inline.  y in place.
// ---------------------------------------------------------------------------
__global__ __launch_bounds__(256)
void scan_kernel(const float* __restrict__ xdbl,
                 float* __restrict__ xz,
                 const float* __restrict__ dt_w,
                 const float* __restrict__ dt_b,
                 const float* __restrict__ A_log,
                 const float* __restrict__ Dp,
                 int layer) {
    int g = blockIdx.x * 256 + threadIdx.x;    // 0 .. B*E-1
    int e = g & (EE - 1), b = g >> 9;

    alignas(16) float dw[RR];
    #pragma unroll
    for (int i = 0; i < RR; i += 4)
        *(float4*)&dw[i] = *(const float4*)(dt_w + ((size_t)layer * EE + e) * RR + i);
    float db = dt_b[layer * EE + e];
    alignas(16) float Ar[NSTATE];
    #pragma unroll
    for (int i = 0; i < NSTATE; i += 4) {
        float4 a4 = *(const float4*)(A_log + ((size_t)layer * EE + e) * NSTATE + i);
        Ar[i + 0] = -expf(a4.x); Ar[i + 1] = -expf(a4.y);
        Ar[i + 2] = -expf(a4.z); Ar[i + 3] = -expf(a4.w);
    }
    float Dv = Dp[layer * EE + e];

    float s[NSTATE];
    #pragma unroll
    for (int n = 0; n < NSTATE; ++n) s[n] = 0.f;

    const float* xd = xdbl + (size_t)b * TT * 48;
    float* xp = xz + (size_t)b * TT * (2 * EE) + e;

    for (int t = 0; t < TT; ++t) {
        const float* row = xd + t * 48;
        float4 r0 = *(const float4*)(row);
        float4 r1 = *(const float4*)(row + 4);
        float4 r2 = *(const float4*)(row + 8);
        float4 r3 = *(const float4*)(row + 12);
        float rr = db;
        rr = fmaf(r0.x, dw[0], rr);  rr = fmaf(r0.y, dw[1], rr);
        rr = fmaf(r0.z, dw[2], rr);  rr = fmaf(r0.w, dw[3], rr);
        rr = fmaf(r1.x, dw[4], rr);  rr = fmaf(r1.y, dw[5], rr);
        rr = fmaf(r1.z, dw[6], rr);  rr = fmaf(r1.w, dw[7], rr);
        rr = fmaf(r2.x, dw[8], rr);  rr = fmaf(r2.y, dw[9], rr);
        rr = fmaf(r2.z, dw[10], rr); rr = fmaf(r2.w, dw[11], rr);
        rr = fmaf(r3.x, dw[12], rr); rr = fmaf(r3.y, dw[13], rr);
        rr = fmaf(r3.z, dw[14], rr); rr = fmaf(r3.w, dw[15], rr);
        float dt = fmaxf(rr, 0.f) + log1pf(__expf(-fabsf(rr)));

        float x_t = xp[(size_t)t * (2 * EE)];
        float dx = dt * x_t;

        alignas(16) float Bv[NSTATE], Cv[NSTATE];
        #pragma unroll
        for (int i = 0; i < NSTATE; i += 4) {
            *(float4*)&Bv[i] = *(const float4*)(row + 16 + i);
            *(float4*)&Cv[i] = *(const float4*)(row + 32 + i);
        }
        float acc = 0.f;
        #pragma unroll
        for (int n = 0; n < NSTATE; ++n) {
            float es = __expf(dt * Ar[n]);
            s[n] = fmaf(s[n], es, dx * Bv[n]);
            acc = fmaf(s[n], Cv[n], acc);
        }
        xp[(size_t)t * (2 * EE)] = acc + x_t * Dv;
    }
}

// ---------------------------------------------------------------------------
// 6. final gather (reconstruct from planes)
// ---------------------------------------------------------------------------
__global__ __launch_bounds__(256)
void gather_out_kernel(const u16* __restrict__ hh, const u16* __restrict__ hl,
                       const int* __restrict__ seq_len,
                       float* __restrict__ out) {
    int b = blockIdx.x;
    int sl = seq_len[b];
    int tl = sl + sl / 2;
    int idx = tl - 1;
    if (idx < 0) idx = 0;
    if (idx > TT - 1) idx = TT - 1;
    size_t src = ((size_t)b * TT + idx) * HH + threadIdx.x;
    out[(size_t)b * HH + threadIdx.x] = bf2f(hh[src]) + bf2f(hl[src]);
}

// ---------------------------------------------------------------------------
// launch
// ---------------------------------------------------------------------------
extern "C" void kernel_launch(void* const* d_in, const int* in_sizes, int n_in,
                              void* d_out, int out_size, void* d_ws, size_t ws_size,
                              hipStream_t stream) {
    const int*   item_seq  = (const int*)  d_in[0];
    const int*   seq_len   = (const int*)  d_in[1];
    const float* item_emb  = (const float*)d_in[2];
    const float* ln_w      = (const float*)d_in[3];
    const float* ln_b      = (const float*)d_in[4];
    const float* in_proj_w = (const float*)d_in[5];
    const float* conv_w    = (const float*)d_in[6];
    const float* conv_b    = (const float*)d_in[7];
    const float* x_proj_w  = (const float*)d_in[8];
    const float* dt_w      = (const float*)d_in[9];
    const float* dt_b      = (const float*)d_in[10];
    const float* A_log     = (const float*)d_in[11];
    const float* Dp        = (const float*)d_in[12];
    const float* out_w     = (const float*)d_in[13];
    const float* mn_w      = (const float*)d_in[14];
    const float* mn_b      = (const float*)d_in[15];
    const float* fc1_w     = (const float*)d_in[16];
    const float* fc1_b     = (const float*)d_in[17];
    const float* fc2_w     = (const float*)d_in[18];
    const float* fc2_b     = (const float*)d_in[19];
    const float* fn_w      = (const float*)d_in[20];
    const float* fn_b      = (const float*)d_in[21];

    // ---- workspace layout: EXACTLY 486,604,800 B (== round-1 proven size) ----
    float* xz   = (float*)d_ws;                       // MTOK*2E f   = 314,572,800 B
    u16*   hh   = (u16*)(xz + (size_t)MTOK * 2 * EE); // MTOK*H u16  =  39,321,600 B
    u16*   hl   = hh + (size_t)MTOK * HH;             //                39,321,600 B
    float* tmp  = (float*)(hl + (size_t)MTOK * HH);   // MTOK*H f    =  78,643,200 B
    float* xdbl = tmp + (size_t)MTOK * HH;            // MTOK*48 f   =  14,745,600 B
    // weight-plane scratch A: aliases xdbl (used only when xdbl dead, and
    // never by the x_proj GEMM which WRITES xdbl)
    u16* wsH = (u16*)xdbl;                            // <=262,144 u16 each
    u16* wsL = wsH + 262144;
    // weight-plane scratch B: aliases tmp (used by x_proj only; tmp dead then)
    u16* wsBH = (u16*)tmp;                            // 24,576 u16 each
    u16* wsBL = wsBH + 24576;
    // fc1 output planes alias xz (xc/z dead by then):
    u16* ffh = (u16*)xz;                              // MTOK*4H u16 = 157,286,400 B
    u16* ffl = ffh + (size_t)MTOK * 4 * HH;           //              157,286,400 B

    // 1. embedding + LN -> h planes
    embed_ln_kernel<<<MTOK, 256, 0, stream>>>(item_seq, item_emb, ln_w, ln_b, hh, hl);

    for (int l = 0; l < NLAYER; ++l) {
        // 2. in_proj: xz = h @ in_proj_w[l]^T   (M x 1024, K=256)
        {
            int nw = 2 * EE * HH;   // 262,144 (xdbl dead here)
            split_kernel<<<nw / 256, 256, 0, stream>>>(
                in_proj_w + (size_t)l * nw, wsH, wsL, nw);
            dim3 grid((2 * EE) / 128, MTOK / 128);
            gemm_mfma<0, 0><<<grid, 256, 0, stream>>>(
                hh, hl, nullptr, 0, wsH, wsL,
                nullptr, xz, nullptr, nullptr, MTOK, 2 * EE, HH);
        }
        // 3. causal depthwise conv + SiLU (in place in xc)
        conv_silu_kernel<<<(BB * EE) / 256, 256, 0, stream>>>(xz, conv_w, conv_b, l);
        // 4. x_proj (MFMA, N=48, K=512): xdbl = xc @ x_proj_w[l]^T
        {
            int nw = 48 * EE;       // 24,576 (tmp dead here)
            split_kernel<<<nw / 256, 256, 0, stream>>>(
                x_proj_w + (size_t)l * nw, wsBH, wsBL, nw);
            dim3 grid(1, MTOK / 128);
            gemm_mfma<2, 0><<<grid, 256, 0, stream>>>(
                nullptr, nullptr, xz, 2 * EE, wsBH, wsBL,
                nullptr, xdbl, nullptr, nullptr, MTOK, 48, EE);
        }
        // 5. selective scan: y in place in xc
        scan_kernel<<<(BB * EE) / 256, 256, 0, stream>>>(
            xdbl, xz, dt_w, dt_b, A_log, Dp, l);
        // 6. out proj: tmp = (y*silu(z)) @ out_w[l]^T   (M x 256, K=512)
        {
            int nw = HH * EE;       // 131,072 (xdbl dead after scan)
            split_kernel<<<nw / 256, 256, 0, stream>>>(
                out_w + (size_t)l * nw, wsH, wsL, nw);
            dim3 grid(HH / 128, MTOK / 128);
            gemm_mfma<1, 0><<<grid, 256, 0, stream>>>(
                nullptr, nullptr, xz, 2 * EE, wsH, wsL,
                nullptr, tmp, nullptr, nullptr, MTOK, HH, EE);
        }
        // 7. h = LN(tmp + h)
        add_ln_kernel<<<MTOK, 256, 0, stream>>>(tmp, hh, hl, mn_w + l * HH, mn_b + l * HH);
        // 8. fc1 + GELU -> ff planes (alias xz)   (M x 1024, K=256)
        {
            int nw = 4 * HH * HH;   // 262,144
            split_kernel<<<nw / 256, 256, 0, stream>>>(
                fc1_w + (size_t)l * nw, wsH, wsL, nw);
            dim3 grid((4 * HH) / 128, MTOK / 128);
            gemm_mfma<0, 1><<<grid, 256, 0, stream>>>(
                hh, hl, nullptr, 0, wsH, wsL,
                fc1_b + (size_t)l * 4 * HH,
                nullptr, ffh, ffl, MTOK, 4 * HH, HH);
        }
        // 9. fc2: tmp = ff @ fc2_w^T + b          (M x 256, K=1024)
        {
            int nw = HH * 4 * HH;   // 262,144
            split_kernel<<<nw / 256, 256, 0, stream>>>(
                fc2_w + (size_t)l * nw, wsH, wsL, nw);
            dim3 grid(HH / 128, MTOK / 128);
            gemm_mfma<0, 0><<<grid, 256, 0, stream>>>(
                ffh, ffl, nullptr, 0, wsH, wsL,
                fc2_b + (size_t)l * HH,
                tmp, nullptr, nullptr, MTOK, HH, 4 * HH);
        }
        // 10. h = LN(tmp + h)
        add_ln_kernel<<<MTOK, 256, 0, stream>>>(tmp, hh, hl, fn_w + l * HH, fn_b + l * HH);
    }

    // 11. gather final position per batch
    gather_out_kernel<<<BB, 256, 0, stream>>>(hh, hl, seq_len, (float*)d_out);
}

// Round 5
// 2678.378 us; speedup vs baseline: 2.4804x; 1.0949x over previous
//
#include <hip/hip_runtime.h>
#include <math.h>

typedef unsigned short u16;
typedef __attribute__((ext_vector_type(8))) short bf8_t;   // 8 bf16 (4 VGPR)
typedef __attribute__((ext_vector_type(4))) float f4_t;    // 4 fp32

#define BB 256
#define LL 200
#define HH 256
#define EE 512
#define NSTATE 16
#define KCONV 4
#define RR 16
#define NLAYER 2
#define VV 150000
#define TT 300
#define MTOK (BB*TT)      // 76800

#define LOG2E 1.44269504088896340736f
#define LN2   0.69314718055994530942f

// ---------------------------------------------------------------------------
// helpers
// ---------------------------------------------------------------------------
__device__ __forceinline__ float siluf(float x) { return x / (1.0f + expf(-x)); }
__device__ __forceinline__ float geluf(float x) {
    return 0.5f * x * (1.0f + erff(x * 0.70710678118654752440f));
}
__device__ __forceinline__ u16 f2bf(float x) {               // RNE float->bf16
    unsigned u = __float_as_uint(x);
    unsigned r = u + 0x7FFF + ((u >> 16) & 1);
    return (u16)(r >> 16);
}
__device__ __forceinline__ float bf2f(u16 b) { return __uint_as_float((unsigned)b << 16); }

__device__ __forceinline__ void gload16(const void* gp, void* lp) {
    __builtin_amdgcn_global_load_lds(
        (const __attribute__((address_space(1))) unsigned int*)gp,
        (__attribute__((address_space(3))) unsigned int*)lp,
        16, 0, 0);
}

__device__ __forceinline__ void block_reduce2(float& a, float& b) {
    __shared__ float ra[4], rb[4];
    #pragma unroll
    for (int o = 32; o > 0; o >>= 1) {
        a += __shfl_down(a, o, 64);
        b += __shfl_down(b, o, 64);
    }
    int lane = threadIdx.x & 63, w = threadIdx.x >> 6;
    if (lane == 0) { ra[w] = a; rb[w] = b; }
    __syncthreads();
    a = ra[0] + ra[1] + ra[2] + ra[3];
    b = rb[0] + rb[1] + rb[2] + rb[3];
}

// ---------------------------------------------------------------------------
// split a fp32 tensor into bf16 hi/lo planes (weights, per-GEMM)
// ---------------------------------------------------------------------------
__global__ __launch_bounds__(256)
void split_kernel(const float* __restrict__ x, u16* __restrict__ ph,
                  u16* __restrict__ pl, int n) {
    int i = blockIdx.x * 256 + threadIdx.x;
    if (i < n) {
        float v = x[i];
        u16 hb = f2bf(v);
        ph[i] = hb;
        pl[i] = f2bf(v - bf2f(hb));
    }
}

// ---------------------------------------------------------------------------
// 1. embedding gather (with interleave) + LayerNorm -> hi/lo planes of h
// ---------------------------------------------------------------------------
__global__ __launch_bounds__(256)
void embed_ln_kernel(const int* __restrict__ item_seq,
                     const float* __restrict__ item_emb,
                     const float* __restrict__ ln_w,
                     const float* __restrict__ ln_b,
                     u16* __restrict__ hh, u16* __restrict__ hl) {
    int tok = blockIdx.x;
    int b = tok / TT, p = tok - b * TT;
    int k = p / 3, r = p - 3 * k;
    int item;
    if (r == 2) item = VV - 1;
    else        item = item_seq[b * LL + 2 * k + r];
    int tid = threadIdx.x;
    float x = item_emb[(size_t)item * HH + tid];
    float s1 = x, s2 = x * x;
    block_reduce2(s1, s2);
    float m = s1 * (1.0f / HH);
    float var = s2 * (1.0f / HH) - m * m;
    float inv = rsqrtf(var + 1e-12f);
    float v = (x - m) * inv * ln_w[tid] + ln_b[tid];
    size_t idx = (size_t)tok * HH + tid;
    u16 hb = f2bf(v);
    hh[idx] = hb;
    hl[idx] = f2bf(v - bf2f(hb));
}

// ---------------------------------------------------------------------------
// 2. residual add + LayerNorm on the hi/lo plane residual stream
// ---------------------------------------------------------------------------
__global__ __launch_bounds__(256)
void add_ln_kernel(const float* __restrict__ tmp,
                   u16* __restrict__ hh, u16* __restrict__ hl,
                   const float* __restrict__ w,
                   const float* __restrict__ bnorm) {
    int tok = blockIdx.x;
    int tid = threadIdx.x;
    size_t idx = (size_t)tok * HH + tid;
    float x = tmp[idx] + bf2f(hh[idx]) + bf2f(hl[idx]);
    float s1 = x, s2 = x * x;
    block_reduce2(s1, s2);
    float m = s1 * (1.0f / HH);
    float var = s2 * (1.0f / HH) - m * m;
    float inv = rsqrtf(var + 1e-12f);
    float v = (x - m) * inv * w[tid] + bnorm[tid];
    u16 hb = f2bf(v);
    hh[idx] = hb;
    hl[idx] = f2bf(v - bf2f(hb));
}

// ---------------------------------------------------------------------------
// 3. split-bf16 MFMA GEMM: C[M,N] = A[M,K] @ W[N,K]^T (+bias)
//    AMODE 0: A = bf16 hi/lo planes (lda=K) via global_load_lds
//    AMODE 1: A = fp32 rows (lda=ldaf): u = y*silu(z at +EE), reg split
//    MODE 0: fp32 C (+bias).  MODE 1: gelu(C+bias) -> hi/lo planes
// ---------------------------------------------------------------------------
template <int AMODE, int MODE>
__global__ __launch_bounds__(256)
void gemm_mfma(const u16* __restrict__ Ah, const u16* __restrict__ Al,
               const float* __restrict__ Af, int ldaf,
               const u16* __restrict__ Wh, const u16* __restrict__ Wl,
               const float* __restrict__ bias,
               float* __restrict__ C,
               u16* __restrict__ Ch, u16* __restrict__ Cl,
               int M, int N, int K) {
    __shared__ u16 sA[2][128 * 32];
    __shared__ u16 sB[2][128 * 32];
    int tid = threadIdx.x;
    int lane = tid & 63, wid = tid >> 6;
    int wr = wid >> 1, wc = wid & 1;

    // XCD-aware bijective swizzle (m204)
    int gx = gridDim.x, nwg = gx * gridDim.y;
    int id = blockIdx.y * gx + blockIdx.x;
    int q = nwg >> 3, rr8 = nwg & 7;
    int xcd = id & 7, pos = id >> 3;
    int nid = (xcd < rr8 ? xcd * (q + 1) : rr8 * (q + 1) + (xcd - rr8) * q) + pos;
    int bn = (nid % gx) * 128;
    int bm = (nid / gx) * 128;

    f4_t acc[4][4];
    #pragma unroll
    for (int i = 0; i < 4; ++i)
        #pragma unroll
        for (int j = 0; j < 4; ++j)
            acc[i][j] = (f4_t){0.f, 0.f, 0.f, 0.f};

    int scol = (lane & 3) * 8;

    for (int k0 = 0; k0 < K; k0 += 32) {
        if (AMODE == 0) {
            #pragma unroll
            for (int qq = 0; qq < 2; ++qq) {
                int row = wid * 32 + qq * 16 + (lane >> 2);
                size_t ga = (size_t)(bm + row) * K + k0 + scol;
                int off = (wid * 2 + qq) * 1024;
                gload16(Ah + ga, (char*)&sA[0][0] + off);
                gload16(Al + ga, (char*)&sA[1][0] + off);
            }
        } else {
            int r = tid >> 1;
            int kc = (tid & 1) * 16;
            size_t base = (size_t)(bm + r) * ldaf + k0 + kc;
            float us[16];
            #pragma unroll
            for (int i = 0; i < 16; i += 4) {
                float4 y4 = *(const float4*)(Af + base + i);
                float4 z4 = *(const float4*)(Af + base + EE + i);
                us[i + 0] = y4.x * (z4.x / (1.f + __expf(-z4.x)));
                us[i + 1] = y4.y * (z4.y / (1.f + __expf(-z4.y)));
                us[i + 2] = y4.z * (z4.z / (1.f + __expf(-z4.z)));
                us[i + 3] = y4.w * (z4.w / (1.f + __expf(-z4.w)));
            }
            alignas(16) u16 hb[16], lb[16];
            #pragma unroll
            for (int i = 0; i < 16; ++i) {
                hb[i] = f2bf(us[i]);
                lb[i] = f2bf(us[i] - bf2f(hb[i]));
            }
            *(bf8_t*)&sA[0][r * 32 + kc]     = *(bf8_t*)&hb[0];
            *(bf8_t*)&sA[0][r * 32 + kc + 8] = *(bf8_t*)&hb[8];
            *(bf8_t*)&sA[1][r * 32 + kc]     = *(bf8_t*)&lb[0];
            *(bf8_t*)&sA[1][r * 32 + kc + 8] = *(bf8_t*)&lb[8];
        }
        #pragma unroll
        for (int qq = 0; qq < 2; ++qq) {
            int row = wid * 32 + qq * 16 + (lane >> 2);
            size_t gb = (size_t)(bn + row) * K + k0 + scol;
            int off = (wid * 2 + qq) * 1024;
            gload16(Wh + gb, (char*)&sB[0][0] + off);
            gload16(Wl + gb, (char*)&sB[1][0] + off);
        }
        __syncthreads();

        int arow = wr * 64 + (lane & 15);
        int koff = (lane >> 4) * 8;
        bf8_t ah[4], al[4];
        #pragma unroll
        for (int fm = 0; fm < 4; ++fm) {
            int r = arow + fm * 16;
            ah[fm] = *(const bf8_t*)&sA[0][r * 32 + koff];
            al[fm] = *(const bf8_t*)&sA[1][r * 32 + koff];
        }
        #pragma unroll
        for (int fn = 0; fn < 4; ++fn) {
            int r = wc * 64 + fn * 16 + (lane & 15);
            bf8_t bh = *(const bf8_t*)&sB[0][r * 32 + koff];
            bf8_t bl = *(const bf8_t*)&sB[1][r * 32 + koff];
            #pragma unroll
            for (int fm = 0; fm < 4; ++fm) {
                acc[fm][fn] = __builtin_amdgcn_mfma_f32_16x16x32_bf16(ah[fm], bh, acc[fm][fn], 0, 0, 0);
                acc[fm][fn] = __builtin_amdgcn_mfma_f32_16x16x32_bf16(ah[fm], bl, acc[fm][fn], 0, 0, 0);
                acc[fm][fn] = __builtin_amdgcn_mfma_f32_16x16x32_bf16(al[fm], bh, acc[fm][fn], 0, 0, 0);
            }
        }
        __syncthreads();
    }

    #pragma unroll
    for (int fn = 0; fn < 4; ++fn) {
        int colg = bn + wc * 64 + fn * 16 + (lane & 15);
        if (colg < N) {
            float bv = (bias != nullptr) ? bias[colg] : 0.f;
            #pragma unroll
            for (int fm = 0; fm < 4; ++fm) {
                #pragma unroll
                for (int j = 0; j < 4; ++j) {
                    int rowg = bm + wr * 64 + fm * 16 + (lane >> 4) * 4 + j;
                    float v = acc[fm][fn][j] + bv;
                    if (MODE == 0) {
                        C[(size_t)rowg * N + colg] = v;
                    } else {
                        v = geluf(v);
                        u16 hbv = f2bf(v);
                        Ch[(size_t)rowg * N + colg] = hbv;
                        Cl[(size_t)rowg * N + colg] = f2bf(v - bf2f(hbv));
                    }
                }
            }
        }
    }
}

// ---------------------------------------------------------------------------
// 3b. narrow x_proj GEMM: xdbl[M,48] = xc[M,K=512] @ W[48,512]^T
//     128-row tile, 4 waves all-M (32 rows each: 2 m-frags x 3 n-frags)
// ---------------------------------------------------------------------------
__global__ __launch_bounds__(256)
void gemm_xproj(const float* __restrict__ Af,          // xz rows, lda = 2E
                const u16* __restrict__ Wh, const u16* __restrict__ Wl,
                float* __restrict__ C) {               // ldc = 48
    __shared__ u16 sA[2][128 * 32];
    __shared__ u16 sB[2][48 * 32];
    int tid = threadIdx.x;
    int lane = tid & 63, wid = tid >> 6;
    int bm = blockIdx.x * 128;

    f4_t acc[2][3];
    #pragma unroll
    for (int i = 0; i < 2; ++i)
        #pragma unroll
        for (int j = 0; j < 3; ++j)
            acc[i][j] = (f4_t){0.f, 0.f, 0.f, 0.f};

    for (int k0 = 0; k0 < EE; k0 += 32) {
        // A: reg-staged fp32 -> split planes
        {
            int r = tid >> 1;
            int kc = (tid & 1) * 16;
            size_t base = (size_t)(bm + r) * (2 * EE) + k0 + kc;
            float us[16];
            #pragma unroll
            for (int i = 0; i < 16; i += 4) {
                float4 y4 = *(const float4*)(Af + base + i);
                us[i + 0] = y4.x; us[i + 1] = y4.y;
                us[i + 2] = y4.z; us[i + 3] = y4.w;
            }
            alignas(16) u16 hb[16], lb[16];
            #pragma unroll
            for (int i = 0; i < 16; ++i) {
                hb[i] = f2bf(us[i]);
                lb[i] = f2bf(us[i] - bf2f(hb[i]));
            }
            *(bf8_t*)&sA[0][r * 32 + kc]     = *(bf8_t*)&hb[0];
            *(bf8_t*)&sA[0][r * 32 + kc + 8] = *(bf8_t*)&hb[8];
            *(bf8_t*)&sA[1][r * 32 + kc]     = *(bf8_t*)&lb[0];
            *(bf8_t*)&sA[1][r * 32 + kc + 8] = *(bf8_t*)&lb[8];
        }
        // B: 48 rows x 32 k, two planes (lanes 0..191)
        if (tid < 192) {
            int row = tid >> 2;
            int c16 = (tid & 3) * 8;
            size_t gb = (size_t)row * EE + k0 + c16;
            gload16(Wh + gb, (char*)&sB[0][0] + tid * 16);
            gload16(Wl + gb, (char*)&sB[1][0] + tid * 16);
        }
        __syncthreads();

        int arow = wid * 32 + (lane & 15);
        int koff = (lane >> 4) * 8;
        bf8_t ah[2], al[2];
        #pragma unroll
        for (int fm = 0; fm < 2; ++fm) {
            int r = arow + fm * 16;
            ah[fm] = *(const bf8_t*)&sA[0][r * 32 + koff];
            al[fm] = *(const bf8_t*)&sA[1][r * 32 + koff];
        }
        #pragma unroll
        for (int fn = 0; fn < 3; ++fn) {
            int r = fn * 16 + (lane & 15);
            bf8_t bh = *(const bf8_t*)&sB[0][r * 32 + koff];
            bf8_t bl = *(const bf8_t*)&sB[1][r * 32 + koff];
            #pragma unroll
            for (int fm = 0; fm < 2; ++fm) {
                acc[fm][fn] = __builtin_amdgcn_mfma_f32_16x16x32_bf16(ah[fm], bh, acc[fm][fn], 0, 0, 0);
                acc[fm][fn] = __builtin_amdgcn_mfma_f32_16x16x32_bf16(ah[fm], bl, acc[fm][fn], 0, 0, 0);
                acc[fm][fn] = __builtin_amdgcn_mfma_f32_16x16x32_bf16(al[fm], bh, acc[fm][fn], 0, 0, 0);
            }
        }
        __syncthreads();
    }

    #pragma unroll
    for (int fn = 0; fn < 3; ++fn) {
        int colg = fn * 16 + (lane & 15);
        #pragma unroll
        for (int fm = 0; fm < 2; ++fm) {
            #pragma unroll
            for (int j = 0; j < 4; ++j) {
                int rowg = bm + wid * 32 + fm * 16 + (lane >> 4) * 4 + j;
                C[(size_t)rowg * 48 + colg] = acc[fm][fn][j];
            }
        }
    }
}

// ---------------------------------------------------------------------------
// 4. causal depthwise conv (K=4) + bias + SiLU, in place, 4-step pipelined
// ---------------------------------------------------------------------------
__global__ __launch_bounds__(256, 1)
void conv_silu_kernel(float* __restrict__ xz,
                      const float* __restrict__ conv_w,
                      const float* __restrict__ conv_b,
                      int layer) {
    int g = blockIdx.x * blockDim.x + threadIdx.x;
    int b = g >> 9, e = g & (EE - 1);
    const float* w = conv_w + ((size_t)layer * EE + e) * KCONV;
    float w0 = w[0], w1 = w[1], w2 = w[2], w3 = w[3];
    float bias = conv_b[layer * EE + e];
    float h0 = 0.f, h1 = 0.f, h2 = 0.f;   // x[t-3..t-1]
    float* p = xz + (size_t)b * TT * (2 * EE) + e;
    float c0 = p[0], c1 = p[1 * 2 * EE], c2 = p[2 * 2 * EE], c3 = p[3 * 2 * EE];
    for (int t = 0; t < TT; t += 4) {
        int t4 = t + 4 < TT ? t + 4 : TT - 1;
        int t5 = t + 5 < TT ? t + 5 : TT - 1;
        int t6 = t + 6 < TT ? t + 6 : TT - 1;
        int t7 = t + 7 < TT ? t + 7 : TT - 1;
        float n0 = p[(size_t)t4 * (2 * EE)];
        float n1 = p[(size_t)t5 * (2 * EE)];
        float n2 = p[(size_t)t6 * (2 * EE)];
        float n3 = p[(size_t)t7 * (2 * EE)];
        float v0 = fmaf(w0, h0, fmaf(w1, h1, fmaf(w2, h2, fmaf(w3, c0, bias))));
        float v1 = fmaf(w0, h1, fmaf(w1, h2, fmaf(w2, c0, fmaf(w3, c1, bias))));
        float v2 = fmaf(w0, h2, fmaf(w1, c0, fmaf(w2, c1, fmaf(w3, c2, bias))));
        float v3 = fmaf(w0, c0, fmaf(w1, c1, fmaf(w2, c2, fmaf(w3, c3, bias))));
        p[(size_t)(t + 0) * (2 * EE)] = v0 / (1.f + __expf(-v0));
        p[(size_t)(t + 1) * (2 * EE)] = v1 / (1.f + __expf(-v1));
        p[(size_t)(t + 2) * (2 * EE)] = v2 / (1.f + __expf(-v2));
        p[(size_t)(t + 3) * (2 * EE)] = v3 / (1.f + __expf(-v3));
        h0 = c1; h1 = c2; h2 = c3;
        c0 = n0; c1 = n1; c2 = n2; c3 = n3;
    }
}

// ---------------------------------------------------------------------------
// 5. selective scan v4: one thread per (b,e); all state in named registers,
//    exp2-native math, tree reductions, 1-step-ahead two-bank pipeline.
// ---------------------------------------------------------------------------
struct Row {
    float4 a0, a1, a2, a3, b0, b1, b2, b3, c0, c1, c2, c3;
};
__device__ __forceinline__ Row ldrow(const float* __restrict__ p) {
    Row r;
    r.a0 = *(const float4*)(p + 0);  r.a1 = *(const float4*)(p + 4);
    r.a2 = *(const float4*)(p + 8);  r.a3 = *(const float4*)(p + 12);
    r.b0 = *(const float4*)(p + 16); r.b1 = *(const float4*)(p + 20);
    r.b2 = *(const float4*)(p + 24); r.b3 = *(const float4*)(p + 28);
    r.c0 = *(const float4*)(p + 32); r.c1 = *(const float4*)(p + 36);
    r.c2 = *(const float4*)(p + 40); r.c3 = *(const float4*)(p + 44);
    return r;
}
__device__ __forceinline__ float4 negexp_l2e(float4 a) {
    float4 r;
    r.x = -__expf(a.x) * LOG2E; r.y = -__expf(a.y) * LOG2E;
    r.z = -__expf(a.z) * LOG2E; r.w = -__expf(a.w) * LOG2E;
    return r;
}

__global__ __launch_bounds__(256, 1)
void scan_kernel(const float* __restrict__ xdbl,
                 float* __restrict__ xz,
                 const float* __restrict__ dt_w,
                 const float* __restrict__ dt_b,
                 const float* __restrict__ A_log,
                 const float* __restrict__ Dp,
                 int layer) {
    int g = blockIdx.x * 256 + threadIdx.x;    // 0 .. B*E-1
    int e = g & (EE - 1), b = g >> 9;

    const float* dwp = dt_w + ((size_t)layer * EE + e) * RR;
    float4 dw0 = *(const float4*)(dwp + 0),  dw1 = *(const float4*)(dwp + 4);
    float4 dw2 = *(const float4*)(dwp + 8),  dw3 = *(const float4*)(dwp + 12);
    float db = dt_b[layer * EE + e];
    const float* alp = A_log + ((size_t)layer * EE + e) * NSTATE;
    float4 Ar0 = negexp_l2e(*(const float4*)(alp + 0));
    float4 Ar1 = negexp_l2e(*(const float4*)(alp + 4));
    float4 Ar2 = negexp_l2e(*(const float4*)(alp + 8));
    float4 Ar3 = negexp_l2e(*(const float4*)(alp + 12));
    float Dv = Dp[layer * EE + e];

    float4 s0 = {0,0,0,0}, s1 = {0,0,0,0}, s2 = {0,0,0,0}, s3 = {0,0,0,0};
    const float* xd = xdbl + (size_t)b * TT * 48;
    float* xp = xz + (size_t)b * TT * (2 * EE) + e;

    auto step = [&](const Row& R, float xv, int t) {
        float p0 = fmaf(R.a0.w, dw0.w, fmaf(R.a0.z, dw0.z, fmaf(R.a0.y, dw0.y, R.a0.x * dw0.x)));
        float p1 = fmaf(R.a1.w, dw1.w, fmaf(R.a1.z, dw1.z, fmaf(R.a1.y, dw1.y, R.a1.x * dw1.x)));
        float p2 = fmaf(R.a2.w, dw2.w, fmaf(R.a2.z, dw2.z, fmaf(R.a2.y, dw2.y, R.a2.x * dw2.x)));
        float p3 = fmaf(R.a3.w, dw3.w, fmaf(R.a3.z, dw3.z, fmaf(R.a3.y, dw3.y, R.a3.x * dw3.x)));
        float rr = db + ((p0 + p1) + (p2 + p3));
        float qv = exp2f(-fabsf(rr) * LOG2E);
        float dt = fmaxf(rr, 0.f) + LN2 * __log2f(1.f + qv);
        float dx = dt * xv;
        float q0, q1, q2, q3, es;
        es = exp2f(dt * Ar0.x); s0.x = fmaf(s0.x, es, dx * R.b0.x); q0 = s0.x * R.c0.x;
        es = exp2f(dt * Ar0.y); s0.y = fmaf(s0.y, es, dx * R.b0.y); q1 = s0.y * R.c0.y;
        es = exp2f(dt * Ar0.z); s0.z = fmaf(s0.z, es, dx * R.b0.z); q2 = s0.z * R.c0.z;
        es = exp2f(dt * Ar0.w); s0.w = fmaf(s0.w, es, dx * R.b0.w); q3 = s0.w * R.c0.w;
        es = exp2f(dt * Ar1.x); s1.x = fmaf(s1.x, es, dx * R.b1.x); q0 = fmaf(s1.x, R.c1.x, q0);
        es = exp2f(dt * Ar1.y); s1.y = fmaf(s1.y, es, dx * R.b1.y); q1 = fmaf(s1.y, R.c1.y, q1);
        es = exp2f(dt * Ar1.z); s1.z = fmaf(s1.z, es, dx * R.b1.z); q2 = fmaf(s1.z, R.c1.z, q2);
        es = exp2f(dt * Ar1.w); s1.w = fmaf(s1.w, es, dx * R.b1.w); q3 = fmaf(s1.w, R.c1.w, q3);
        es = exp2f(dt * Ar2.x); s2.x = fmaf(s2.x, es, dx * R.b2.x); q0 = fmaf(s2.x, R.c2.x, q0);
        es = exp2f(dt * Ar2.y); s2.y = fmaf(s2.y, es, dx * R.b2.y); q1 = fmaf(s2.y, R.c2.y, q1);
        es = exp2f(dt * Ar2.z); s2.z = fmaf(s2.z, es, dx * R.b2.z); q2 = fmaf(s2.z, R.c2.z, q2);
        es = exp2f(dt * Ar2.w); s2.w = fmaf(s2.w, es, dx * R.b2.w); q3 = fmaf(s2.w, R.c2.w, q3);
        es = exp2f(dt * Ar3.x); s3.x = fmaf(s3.x, es, dx * R.b3.x); q0 = fmaf(s3.x, R.c3.x, q0);
        es = exp2f(dt * Ar3.y); s3.y = fmaf(s3.y, es, dx * R.b3.y); q1 = fmaf(s3.y, R.c3.y, q1);
        es = exp2f(dt * Ar3.z); s3.z = fmaf(s3.z, es, dx * R.b3.z); q2 = fmaf(s3.z, R.c3.z, q2);
        es = exp2f(dt * Ar3.w); s3.w = fmaf(s3.w, es, dx * R.b3.w); q3 = fmaf(s3.w, R.c3.w, q3);
        xp[(size_t)t * (2 * EE)] = ((q0 + q1) + (q2 + q3)) + xv * Dv;
    };

    Row r0 = ldrow(xd);
    float x0v = xp[0];
    for (int t = 0; t < TT; t += 2) {
        Row r1 = ldrow(xd + (size_t)(t + 1) * 48);
        float x1v = xp[(size_t)(t + 1) * (2 * EE)];
        step(r0, x0v, t);
        int tb = (t + 2 < TT) ? t + 2 : TT - 1;
        r0 = ldrow(xd + (size_t)tb * 48);
        x0v = xp[(size_t)tb * (2 * EE)];
        step(r1, x1v, t + 1);
    }
}

// ---------------------------------------------------------------------------
// 6. final gather (reconstruct from planes)
// ---------------------------------------------------------------------------
__global__ __launch_bounds__(256)
void gather_out_kernel(const u16* __restrict__ hh, const u16* __restrict__ hl,
                       const int* __restrict__ seq_len,
                       float* __restrict__ out) {
    int b = blockIdx.x;
    int sl = seq_len[b];
    int tl = sl + sl / 2;
    int idx = tl - 1;
    if (idx < 0) idx = 0;
    if (idx > TT - 1) idx = TT - 1;
    size_t src = ((size_t)b * TT + idx) * HH + threadIdx.x;
    out[(size_t)b * HH + threadIdx.x] = bf2f(hh[src]) + bf2f(hl[src]);
}

// ---------------------------------------------------------------------------
// launch
// ---------------------------------------------------------------------------
extern "C" void kernel_launch(void* const* d_in, const int* in_sizes, int n_in,
                              void* d_out, int out_size, void* d_ws, size_t ws_size,
                              hipStream_t stream) {
    const int*   item_seq  = (const int*)  d_in[0];
    const int*   seq_len   = (const int*)  d_in[1];
    const float* item_emb  = (const float*)d_in[2];
    const float* ln_w      = (const float*)d_in[3];
    const float* ln_b      = (const float*)d_in[4];
    const float* in_proj_w = (const float*)d_in[5];
    const float* conv_w    = (const float*)d_in[6];
    const float* conv_b    = (const float*)d_in[7];
    const float* x_proj_w  = (const float*)d_in[8];
    const float* dt_w      = (const float*)d_in[9];
    const float* dt_b      = (const float*)d_in[10];
    const float* A_log     = (const float*)d_in[11];
    const float* Dp        = (const float*)d_in[12];
    const float* out_w     = (const float*)d_in[13];
    const float* mn_w      = (const float*)d_in[14];
    const float* mn_b      = (const float*)d_in[15];
    const float* fc1_w     = (const float*)d_in[16];
    const float* fc1_b     = (const float*)d_in[17];
    const float* fc2_w     = (const float*)d_in[18];
    const float* fc2_b     = (const float*)d_in[19];
    const float* fn_w      = (const float*)d_in[20];
    const float* fn_b      = (const float*)d_in[21];

    // ---- workspace layout: EXACTLY 486,604,800 B (round-1 proven size) ----
    float* xz   = (float*)d_ws;                       // MTOK*2E f   = 314,572,800 B
    u16*   hh   = (u16*)(xz + (size_t)MTOK * 2 * EE); // MTOK*H u16  =  39,321,600 B
    u16*   hl   = hh + (size_t)MTOK * HH;             //                39,321,600 B
    float* tmp  = (float*)(hl + (size_t)MTOK * HH);   // MTOK*H f    =  78,643,200 B
    float* xdbl = tmp + (size_t)MTOK * HH;            // MTOK*48 f   =  14,745,600 B
    u16* wsH = (u16*)xdbl;                            // weight planes (alias xdbl)
    u16* wsL = wsH + 262144;
    u16* wsBH = (u16*)tmp;                            // x_proj planes (alias tmp)
    u16* wsBL = wsBH + 24576;
    u16* ffh = (u16*)xz;                              // fc1 out planes (alias xz)
    u16* ffl = ffh + (size_t)MTOK * 4 * HH;

    embed_ln_kernel<<<MTOK, 256, 0, stream>>>(item_seq, item_emb, ln_w, ln_b, hh, hl);

    for (int l = 0; l < NLAYER; ++l) {
        // in_proj
        {
            int nw = 2 * EE * HH;
            split_kernel<<<nw / 256, 256, 0, stream>>>(
                in_proj_w + (size_t)l * nw, wsH, wsL, nw);
            dim3 grid((2 * EE) / 128, MTOK / 128);
            gemm_mfma<0, 0><<<grid, 256, 0, stream>>>(
                hh, hl, nullptr, 0, wsH, wsL,
                nullptr, xz, nullptr, nullptr, MTOK, 2 * EE, HH);
        }
        // conv
        conv_silu_kernel<<<(BB * EE) / 256, 256, 0, stream>>>(xz, conv_w, conv_b, l);
        // x_proj (narrow MFMA)
        {
            int nw = 48 * EE;
            split_kernel<<<nw / 256, 256, 0, stream>>>(
                x_proj_w + (size_t)l * nw, wsBH, wsBL, nw);
            gemm_xproj<<<MTOK / 128, 256, 0, stream>>>(xz, wsBH, wsBL, xdbl);
        }
        // scan
        scan_kernel<<<(BB * EE) / 256, 256, 0, stream>>>(
            xdbl, xz, dt_w, dt_b, A_log, Dp, l);
        // out proj (fused y*silu(z))
        {
            int nw = HH * EE;
            split_kernel<<<nw / 256, 256, 0, stream>>>(
                out_w + (size_t)l * nw, wsH, wsL, nw);
            dim3 grid(HH / 128, MTOK / 128);
            gemm_mfma<1, 0><<<grid, 256, 0, stream>>>(
                nullptr, nullptr, xz, 2 * EE, wsH, wsL,
                nullptr, tmp, nullptr, nullptr, MTOK, HH, EE);
        }
        add_ln_kernel<<<MTOK, 256, 0, stream>>>(tmp, hh, hl, mn_w + l * HH, mn_b + l * HH);
        // fc1 + GELU
        {
            int nw = 4 * HH * HH;
            split_kernel<<<nw / 256, 256, 0, stream>>>(
                fc1_w + (size_t)l * nw, wsH, wsL, nw);
            dim3 grid((4 * HH) / 128, MTOK / 128);
            gemm_mfma<0, 1><<<grid, 256, 0, stream>>>(
                hh, hl, nullptr, 0, wsH, wsL,
                fc1_b + (size_t)l * 4 * HH,
                nullptr, ffh, ffl, MTOK, 4 * HH, HH);
        }
        // fc2
        {
            int nw = HH * 4 * HH;
            split_kernel<<<nw / 256, 256, 0, stream>>>(
                fc2_w + (size_t)l * nw, wsH, wsL, nw);
            dim3 grid(HH / 128, MTOK / 128);
            gemm_mfma<0, 0><<<grid, 256, 0, stream>>>(
                ffh, ffl, nullptr, 0, wsH, wsL,
                fc2_b + (size_t)l * HH,
                tmp, nullptr, nullptr, MTOK, HH, 4 * HH);
        }
        add_ln_kernel<<<MTOK, 256, 0, stream>>>(tmp, hh, hl, fn_w + l * HH, fn_b + l * HH);
    }

    gather_out_kernel<<<BB, 256, 0, stream>>>(hh, hl, seq_len, (float*)d_out);
}